// Round 8
// baseline (863.460 us; speedup 1.0000x reference)
//
#include <hip/hip_runtime.h>
#include <math.h>

#define N1 8192
#define N2 8192
#define NBATCH 2
#define NBK 512            // candidate buckets per coordinate
#define QBK 1024           // query sort buckets: (mode<<9) | coordbucket
#define QCAP 96            // per-lane survivor capacity

typedef unsigned int uint;
typedef unsigned short ushort;
typedef unsigned long long ull;

__device__ __forceinline__ int bux(float x) {
  int b = (int)floorf((x + 4.0f) * 64.0f);
  return min(max(b, 0), NBK - 1);
}
__device__ __forceinline__ int bur(float r) {
  int b = (int)floorf(r * 64.0f);
  return min(max(b, 0), NBK - 1);
}

// Insert key into ascending sorted 16-array (branchless bubble; largest falls off).
__device__ __forceinline__ void ins16(ull* K, ull key) {
  #pragma unroll
  for (int s = 0; s < 16; ++s) {
    bool lt = key < K[s];
    ull mn = lt ? key : K[s];
    ull mx = lt ? K[s] : key;
    K[s] = mn;
    key = mx;
  }
}

// ---------- build: candidates sorted by x-bucket AND by |p|-bucket; packed flows ----------
__global__ __launch_bounds__(1024) void pw3_build(
    const float* __restrict__ xyz1, const float* __restrict__ flow1,
    float4* __restrict__ sp4x, float4* __restrict__ sp4r,
    float4* __restrict__ f1p, uint* __restrict__ offsx, uint* __restrict__ offsr) {
  __shared__ uint hx[NBK], hr[NBK], sx[NBK], sr[NBK];
  int b = blockIdx.x, t = threadIdx.x;
  if (t < NBK) { hx[t] = 0; hr[t] = 0; }
  __syncthreads();
  const float* x1 = xyz1 + b * 3 * N1;
  const float* f1 = flow1 + b * 3 * N1;
  float px[8], py[8], pz[8];
  int bkx[8], bkr[8];
  #pragma unroll
  for (int r = 0; r < 8; ++r) {
    int m = r * 1024 + t;
    float fx = f1[m], fy = f1[N1 + m], fz = f1[2 * N1 + m];
    px[r] = x1[m] + fx;
    py[r] = x1[N1 + m] + fy;
    pz[r] = x1[2 * N1 + m] + fz;
    f1p[(b << 13) + m] = make_float4(fx, fy, fz, 0.f);
    bkx[r] = bux(px[r]);
    bkr[r] = bur(sqrtf(px[r] * px[r] + py[r] * py[r] + pz[r] * pz[r]));
    atomicAdd(&hx[bkx[r]], 1u);
    atomicAdd(&hr[bkr[r]], 1u);
  }
  __syncthreads();
  uint vx = 0, vr = 0;
  if (t < NBK) { vx = hx[t]; vr = hr[t]; sx[t] = vx; sr[t] = vr; }
  __syncthreads();
  for (int off = 1; off < NBK; off <<= 1) {
    uint ax = 0, ar = 0;
    if (t < NBK && t >= off) { ax = sx[t - off]; ar = sr[t - off]; }
    __syncthreads();
    if (t < NBK) { sx[t] += ax; sr[t] += ar; }
    __syncthreads();
  }
  if (t < NBK) {
    uint ex = sx[t] - vx, er = sr[t] - vr;
    offsx[(b << 9) + t] = ex;
    offsr[(b << 9) + t] = er;
    hx[t] = ex;   // reuse as cursors
    hr[t] = er;
  }
  __syncthreads();
  #pragma unroll
  for (int r = 0; r < 8; ++r) {
    int m = r * 1024 + t;
    float4 v = make_float4(px[r], py[r], pz[r], __int_as_float(m));
    uint p1 = atomicAdd(&hx[bkx[r]], 1u);
    sp4x[(b << 13) + p1] = v;
    uint p2 = atomicAdd(&hr[bkr[r]], 1u);
    sp4r[(b << 13) + p2] = v;
  }
}

// ---------- qsort: per-query radius R + scan mode; counting-sort queries ----------
__global__ __launch_bounds__(1024) void pw3_qsort(
    const float* __restrict__ xyz2, const uint* __restrict__ offsx,
    const uint* __restrict__ offsr, float4* __restrict__ qs4,
    float* __restrict__ qR) {
  __shared__ uint hq[QBK], sq[QBK];
  int b = blockIdx.x, t = threadIdx.x;
  hq[t] = 0;
  __syncthreads();
  const float* x2 = xyz2 + b * 3 * N2;
  float qx[8], qy[8], qz[8], Rr[8];
  int key[8];
  #pragma unroll
  for (int r = 0; r < 8; ++r) {
    int n = r * 1024 + t;
    float X = x2[n], Y = x2[N2 + n], Z = x2[2 * N2 + n];
    qx[r] = X; qy[r] = Y; qz[r] = Z;
    float rr = X * X + Y * Y + Z * Z;
    // Solve (Gaussian box-count over p1 ~ N(0, 1.01 I3)) == T via fixed point.
    const float T = 70.f;             // box target -> ball count ~ 35 >= 16 w.h.p.
    const float IS2 = 0.70360f;       // 1/(sigma*sqrt(2)), sigma^2 = 1.01
    float R = cbrtf(3.2225e-2f * expf(rr * 0.49505f));  // center-density seed
    R = fminf(R, 6.f);
    #pragma unroll
    for (int it = 0; it < 4; ++it) {
      float g = 8192.f
        * (0.5f * (erff((X + R) * IS2) - erff((X - R) * IS2)))
        * (0.5f * (erff((Y + R) * IS2) - erff((Y - R) * IS2)))
        * (0.5f * (erff((Z + R) * IS2) - erff((Z - R) * IS2)));
      R = R * cbrtf(T / fmaxf(g, 1.f));
      R = fminf(R, 8.f);
    }
    R *= 1.05f;
    Rr[r] = R;
    float rl = sqrtf(rr);
    int bxl = bux(X - R), bxh = bux(X + R);
    int brl = bur(rl - R), brh = bur(rl + R);
    uint jx1 = offsx[(b << 9) + bxl];
    uint jx2 = (bxh >= NBK - 1) ? 8192u : offsx[(b << 9) + bxh + 1];
    uint jr1 = offsr[(b << 9) + brl];
    uint jr2 = (brh >= NBK - 1) ? 8192u : offsr[(b << 9) + brh + 1];
    int mode = ((jr2 - jr1) < (jx2 - jx1)) ? 1 : 0;
    int cb = mode ? bur(rl) : bux(X);
    key[r] = (mode << 9) | cb;
    atomicAdd(&hq[key[r]], 1u);
  }
  __syncthreads();
  uint v = hq[t];
  sq[t] = v;
  __syncthreads();
  for (int off = 1; off < QBK; off <<= 1) {
    uint a = 0;
    if (t >= off) a = sq[t - off];
    __syncthreads();
    sq[t] += a;
    __syncthreads();
  }
  hq[t] = sq[t] - v;   // cursor
  __syncthreads();
  #pragma unroll
  for (int r = 0; r < 8; ++r) {
    int n = r * 1024 + t;
    uint pos = atomicAdd(&hq[key[r]], 1u);
    int mode = key[r] >> 9;
    qs4[(b << 13) + pos] = make_float4(qx[r], qy[r], qz[r],
                                       __int_as_float(n | (mode << 13)));
    qR[(b << 13) + pos] = Rr[r];
  }
}

// ---------- sweep: one wave per 64 sorted queries; per-lane exact top-16 ----------
__global__ __launch_bounds__(64) void pw3_sweep(
    const float4* __restrict__ sp4x, const float4* __restrict__ sp4r,
    const float4* __restrict__ f1p, const uint* __restrict__ offsx,
    const uint* __restrict__ offsr, const float4* __restrict__ qs4,
    const float* __restrict__ qR, float* __restrict__ out) {
  __shared__ ushort surv[64 * QCAP];
  __shared__ float4 stage[64];
  int lane = threadIdx.x;
  int w = blockIdx.x;
  int b = w >> 7, g = w & 127;
  float4 q = qs4[(b << 13) + g * 64 + lane];
  int payload = __float_as_int(q.w);
  int n = payload & 8191;
  int mode = __builtin_amdgcn_readfirstlane((payload >> 13) & 1);
  const float4* __restrict__ arr = mode ? sp4r + ((size_t)b << 13)
                                        : sp4x + ((size_t)b << 13);
  const uint* __restrict__ offs = mode ? offsr + (b << 9) : offsx + (b << 9);
  float cc = mode ? sqrtf(q.x * q.x + q.y * q.y + q.z * q.z) : q.x;
  float R = qR[(b << 13) + g * 64 + lane];
  float Rsq = R * R;

  ull K[16];
  #pragma unroll
  for (int s = 0; s < 16; ++s) K[s] = ~0ull;
  int cnt = 0;
  bool alive = true;
  int attempt = 0;

  while (__ballot(alive)) {
    int blo, bhi;
    if (attempt >= 6) { blo = 0; bhi = NBK - 1; Rsq = INFINITY; }
    else if (mode)    { blo = bur(cc - R); bhi = bur(cc + R); }
    else              { blo = bux(cc - R); bhi = bux(cc + R); }
    uint jlo = offs[blo];
    uint jhi = (bhi >= NBK - 1) ? 8192u : offs[bhi + 1];
    int cl = alive ? (int)(jlo >> 6) : 0x7fffffff;
    int ch = alive ? (int)((jhi + 63) >> 6) : 0;
    #pragma unroll
    for (int o = 32; o; o >>= 1) {
      cl = min(cl, __shfl_xor(cl, o));
      ch = max(ch, __shfl_xor(ch, o));
    }
    ch = min(ch, 128);
    if (cl < ch) {
      float4 pre = arr[cl * 64 + lane];
      for (int c = cl; c < ch; ++c) {
        float4 nxt = (c + 1 < ch) ? arr[(c + 1) * 64 + lane] : pre;
        // wave-synchronous LDS staging (single wave: no s_barrier needed)
        asm volatile("s_waitcnt lgkmcnt(0)" ::: "memory");  // prior reads done
        stage[lane] = pre;
        asm volatile("s_waitcnt lgkmcnt(0)" ::: "memory");  // write visible
        int base = c * 64;
        #pragma unroll 8
        for (int t = 0; t < 64; ++t) {
          float4 v = stage[t];   // ds_read_b128 broadcast (uniform addr)
          float dx = v.x - q.x, dy = v.y - q.y, dz = v.z - q.z;
          float d = fmaf(dz, dz, fmaf(dy, dy, dx * dx));
          if (alive && d <= Rsq) {
            if (cnt < QCAP) {
              surv[lane * QCAP + cnt] = (ushort)(base + t);
            } else {
              ull key = (((ull)__float_as_uint(d)) << 13) |
                        (uint)(__float_as_int(v.w));
              if (key < K[15]) ins16(K, key);
            }
            cnt++;
          }
        }
        pre = nxt;
      }
    }
    bool fail = alive && (cnt < 16);
    if (fail) {
      R *= 2.f;
      Rsq = R * R;
      cnt = 0;
      #pragma unroll
      for (int s = 0; s < 16; ++s) K[s] = ~0ull;
    }
    alive = fail;
    attempt++;
  }

  // per-lane exact resolve of buffered survivors
  int mc = min(cnt, QCAP);
  int mx = mc;
  #pragma unroll
  for (int o = 32; o; o >>= 1) mx = max(mx, __shfl_xor(mx, o));
  for (int s = 0; s < mx; ++s) {
    if (s < mc) {
      int pos = surv[lane * QCAP + s];
      float4 v = arr[pos];
      float dx = v.x - q.x, dy = v.y - q.y, dz = v.z - q.z;
      float d = fmaf(dz, dz, fmaf(dy, dy, dx * dx));
      ull key = (((ull)__float_as_uint(d)) << 13) | (uint)(__float_as_int(v.w));
      if (key < K[15]) ins16(K, key);
    }
  }

  // gather flows in ascending (d, idx) order == top_k order
  float fx = 0.f, fy = 0.f, fz = 0.f;
  const float4* __restrict__ fp = f1p + ((size_t)b << 13);
  #pragma unroll
  for (int s = 0; s < 16; ++s) {
    uint idx = (uint)(K[s] & 8191u);
    float4 f = fp[idx];
    fx += f.x; fy += f.y; fz += f.z;
  }
  float* op = out + b * 3 * N2;
  op[n]           = q.x - fx * 0.0625f;
  op[N2 + n]      = q.y - fy * 0.0625f;
  op[2 * N2 + n]  = q.z - fz * 0.0625f;
}

extern "C" void kernel_launch(void* const* d_in, const int* in_sizes, int n_in,
                              void* d_out, int out_size, void* d_ws, size_t ws_size,
                              hipStream_t stream) {
  const float* xyz1  = (const float*)d_in[0];
  const float* xyz2  = (const float*)d_in[1];
  const float* flow1 = (const float*)d_in[2];
  float* out = (float*)d_out;

  char* w = (char*)d_ws;
  float4* sp4x = (float4*)w;  w += (size_t)NBATCH * N1 * sizeof(float4);   // 256 KB
  float4* sp4r = (float4*)w;  w += (size_t)NBATCH * N1 * sizeof(float4);   // 256 KB
  float4* f1p  = (float4*)w;  w += (size_t)NBATCH * N1 * sizeof(float4);   // 256 KB
  float4* qs4  = (float4*)w;  w += (size_t)NBATCH * N2 * sizeof(float4);   // 256 KB
  float* qR    = (float*)w;   w += (size_t)NBATCH * N2 * sizeof(float);    // 64 KB
  uint* offsx  = (uint*)w;    w += NBATCH * NBK * sizeof(uint);            // 4 KB
  uint* offsr  = (uint*)w;    w += NBATCH * NBK * sizeof(uint);            // 4 KB

  pw3_build<<<NBATCH, 1024, 0, stream>>>(xyz1, flow1, sp4x, sp4r, f1p, offsx, offsr);
  pw3_qsort<<<NBATCH, 1024, 0, stream>>>(xyz2, offsx, offsr, qs4, qR);
  pw3_sweep<<<(NBATCH * N2) / 64, 64, 0, stream>>>(sp4x, sp4r, f1p, offsx, offsr,
                                                   qs4, qR, out);
}

// Round 10
// 299.491 us; speedup vs baseline: 2.8831x; 2.8831x over previous
//
#include <hip/hip_runtime.h>
#include <math.h>

#define N1 8192
#define N2 8192
#define NBATCH 2
#define NBK 512            // candidate buckets per coordinate
#define QBK 1024           // query sort buckets: (mode<<9) | coordbucket
#define QCAP 48            // per-wave per-lane survivor capacity (+1 scratch row)

typedef unsigned int uint;
typedef unsigned short ushort;
typedef unsigned long long ull;

__device__ __forceinline__ int bux(float x) {
  int b = (int)floorf((x + 4.0f) * 64.0f);
  return min(max(b, 0), NBK - 1);
}
__device__ __forceinline__ int bur(float r) {
  int b = (int)floorf(r * 64.0f);
  return min(max(b, 0), NBK - 1);
}
// Insert key into ascending sorted 16-array (branchless bubble).
__device__ __forceinline__ void ins16(ull* K, ull key) {
  #pragma unroll
  for (int s = 0; s < 16; ++s) {
    bool lt = key < K[s];
    ull mn = lt ? key : K[s];
    ull mx = lt ? K[s] : key;
    K[s] = mn;
    key = mx;
  }
}
__device__ __forceinline__ float rlf(float v, int l) {
  return __builtin_bit_cast(
      float, __builtin_amdgcn_readlane(__builtin_bit_cast(int, v), l));
}

// ---------- build: candidates sorted by x-bucket AND |p|-bucket; packed flows ----------
__global__ __launch_bounds__(1024) void pw3_build(
    const float* __restrict__ xyz1, const float* __restrict__ flow1,
    float4* __restrict__ sp4x, float4* __restrict__ sp4r,
    float4* __restrict__ f1p, uint* __restrict__ offsx, uint* __restrict__ offsr) {
  __shared__ uint hx[NBK], hr[NBK], sx[NBK], sr[NBK];
  int b = blockIdx.x, t = threadIdx.x;
  if (t < NBK) { hx[t] = 0; hr[t] = 0; }
  __syncthreads();
  const float* x1 = xyz1 + b * 3 * N1;
  const float* f1 = flow1 + b * 3 * N1;
  float px[8], py[8], pz[8];
  int bkx[8], bkr[8];
  #pragma unroll
  for (int r = 0; r < 8; ++r) {
    int m = r * 1024 + t;
    float fx = f1[m], fy = f1[N1 + m], fz = f1[2 * N1 + m];
    px[r] = x1[m] + fx;
    py[r] = x1[N1 + m] + fy;
    pz[r] = x1[2 * N1 + m] + fz;
    f1p[(b << 13) + m] = make_float4(fx, fy, fz, 0.f);
    bkx[r] = bux(px[r]);
    bkr[r] = bur(sqrtf(px[r] * px[r] + py[r] * py[r] + pz[r] * pz[r]));
    atomicAdd(&hx[bkx[r]], 1u);
    atomicAdd(&hr[bkr[r]], 1u);
  }
  __syncthreads();
  uint vx = 0, vr = 0;
  if (t < NBK) { vx = hx[t]; vr = hr[t]; sx[t] = vx; sr[t] = vr; }
  __syncthreads();
  for (int off = 1; off < NBK; off <<= 1) {
    uint ax = 0, ar = 0;
    if (t < NBK && t >= off) { ax = sx[t - off]; ar = sr[t - off]; }
    __syncthreads();
    if (t < NBK) { sx[t] += ax; sr[t] += ar; }
    __syncthreads();
  }
  if (t < NBK) {
    uint ex = sx[t] - vx, er = sr[t] - vr;
    offsx[(b << 9) + t] = ex;
    offsr[(b << 9) + t] = er;
    hx[t] = ex;   // reuse as cursors
    hr[t] = er;
  }
  __syncthreads();
  #pragma unroll
  for (int r = 0; r < 8; ++r) {
    int m = r * 1024 + t;
    float4 v = make_float4(px[r], py[r], pz[r], __int_as_float(m));
    uint p1 = atomicAdd(&hx[bkx[r]], 1u);
    sp4x[(b << 13) + p1] = v;
    uint p2 = atomicAdd(&hr[bkr[r]], 1u);
    sp4r[(b << 13) + p2] = v;
  }
}

// ---------- qprep (grid-wide): per-query radius R + sort key ----------
__global__ __launch_bounds__(256) void pw3_qprep(
    const float* __restrict__ xyz2, const uint* __restrict__ offsx,
    const uint* __restrict__ offsr, int* __restrict__ gkey,
    float* __restrict__ gR) {
  int i = blockIdx.x * 256 + threadIdx.x;   // 0 .. B*N2-1
  int b = i >> 13, n = i & 8191;
  const float* x2 = xyz2 + b * 3 * N2;
  float X = x2[n], Y = x2[N2 + n], Z = x2[2 * N2 + n];
  float rr = X * X + Y * Y + Z * Z;
  const float T = 70.f;             // box target -> ball count ~ 35 >= 16 w.h.p.
  const float IS2 = 0.70360f;       // 1/(sigma*sqrt(2)), sigma^2 = 1.01
  float R = cbrtf(3.2225e-2f * expf(rr * 0.49505f));
  R = fminf(R, 6.f);
  #pragma unroll
  for (int it = 0; it < 4; ++it) {
    float g = 8192.f
      * (0.5f * (erff((X + R) * IS2) - erff((X - R) * IS2)))
      * (0.5f * (erff((Y + R) * IS2) - erff((Y - R) * IS2)))
      * (0.5f * (erff((Z + R) * IS2) - erff((Z - R) * IS2)));
    R = R * cbrtf(T / fmaxf(g, 1.f));
    R = fminf(R, 8.f);
  }
  R *= 1.05f;
  float rl = sqrtf(rr);
  int bxl = bux(X - R), bxh = bux(X + R);
  int brl = bur(rl - R), brh = bur(rl + R);
  uint jx1 = offsx[(b << 9) + bxl];
  uint jx2 = (bxh >= NBK - 1) ? 8192u : offsx[(b << 9) + bxh + 1];
  uint jr1 = offsr[(b << 9) + brl];
  uint jr2 = (brh >= NBK - 1) ? 8192u : offsr[(b << 9) + brh + 1];
  int mode = ((jr2 - jr1) < (jx2 - jx1)) ? 1 : 0;
  int cb = mode ? bur(rl) : bux(X);
  gkey[i] = (mode << 9) | cb;
  gR[i] = R;
}

// ---------- qsort: counting-sort queries by precomputed key ----------
__global__ __launch_bounds__(1024) void pw3_qsort(
    const float* __restrict__ xyz2, const int* __restrict__ gkey,
    const float* __restrict__ gR, float4* __restrict__ qs4,
    float* __restrict__ qR) {
  __shared__ uint hq[QBK], sq[QBK];
  int b = blockIdx.x, t = threadIdx.x;
  hq[t] = 0;
  __syncthreads();
  int key[8];
  #pragma unroll
  for (int r = 0; r < 8; ++r) {
    key[r] = gkey[(b << 13) + r * 1024 + t];
    atomicAdd(&hq[key[r]], 1u);
  }
  __syncthreads();
  uint v = hq[t];
  sq[t] = v;
  __syncthreads();
  for (int off = 1; off < QBK; off <<= 1) {
    uint a = 0;
    if (t >= off) a = sq[t - off];
    __syncthreads();
    sq[t] += a;
    __syncthreads();
  }
  hq[t] = sq[t] - v;   // cursor
  __syncthreads();
  const float* x2 = xyz2 + b * 3 * N2;
  #pragma unroll
  for (int r = 0; r < 8; ++r) {
    int n = r * 1024 + t;
    uint pos = atomicAdd(&hq[key[r]], 1u);
    int mode = key[r] >> 9;
    qs4[(b << 13) + pos] = make_float4(x2[n], x2[N2 + n], x2[2 * N2 + n],
                                       __int_as_float(n | (mode << 13)));
    qR[(b << 13) + pos] = gR[(b << 13) + n];
  }
}

// ---------- sweep: 4 waves per 64-query group; lane-per-query; readlane broadcast ----------
__global__ __launch_bounds__(256) void pw3_sweep(
    const float4* __restrict__ sp4x, const float4* __restrict__ sp4r,
    const float4* __restrict__ f1p, const uint* __restrict__ offsx,
    const uint* __restrict__ offsr, const float4* __restrict__ qs4,
    const float* __restrict__ qR, float* __restrict__ out) {
  __shared__ ushort surv[(QCAP + 1) * 256];   // [slot][tid], row 48 = scratch
  __shared__ ull keysL[16 * 256];             // [s][tid]
  __shared__ uint cnts[256];
  __shared__ int again;

  int tid = threadIdx.x;
  int lane = tid & 63;
  int w = tid >> 6;
  int g = blockIdx.x;
  int b = g >> 7, grp = g & 127;

  float4 q = qs4[(b << 13) + grp * 64 + lane];
  int payload = __float_as_int(q.w);
  int n = payload & 8191;
  int mode = (__builtin_amdgcn_readlane(payload, 0) >> 13) & 1;  // group mode
  const float4* __restrict__ arr = mode ? sp4r + ((size_t)b << 13)
                                        : sp4x + ((size_t)b << 13);
  const uint* __restrict__ offs = mode ? offsr + (b << 9) : offsx + (b << 9);
  float cc = mode ? sqrtf(q.x * q.x + q.y * q.y + q.z * q.z) : q.x;
  float R = qR[(b << 13) + grp * 64 + lane];
  float Rsq = R * R;

  ull K[16];
  #pragma unroll
  for (int s = 0; s < 16; ++s) K[s] = ~0ull;
  int cnt = 0;
  bool alive = true;
  int attempt = 0;

  while (true) {
    if (attempt < 6) {
      int blo_ = mode ? bur(cc - R) : bux(cc - R);
      int bhi_ = mode ? bur(cc + R) : bux(cc + R);
      uint jlo = offs[blo_];
      uint jhi = (bhi_ >= NBK - 1) ? 8192u : offs[bhi_ + 1];
      int cl = alive ? (int)(jlo >> 6) : 0x7FFFFFFF;
      int ch = alive ? (int)((jhi + 63) >> 6) : -1;
      #pragma unroll
      for (int o = 32; o; o >>= 1) {
        cl = min(cl, __shfl_xor(cl, o));
        ch = max(ch, __shfl_xor(ch, o));
      }
      if (cl < ch) {
        int nch = ch - cl;
        int mc0 = cl + (nch * w) / 4;       // this wave's chunk sub-range
        int mc1 = cl + (nch * (w + 1)) / 4;
        if (mc0 < mc1) {
          float4 vc = arr[mc0 * 64 + lane];
          for (int c = mc0; c < mc1; ++c) {
            int cn = (c + 1 < mc1) ? c + 1 : c;
            float4 vn = arr[cn * 64 + lane];     // prefetch next chunk
            int base = c * 64;
            #pragma unroll
            for (int t = 0; t < 64; ++t) {
              float sxx = rlf(vc.x, t), syy = rlf(vc.y, t), szz = rlf(vc.z, t);
              float dx = q.x - sxx, dy = q.y - syy, dz = q.z - szz;
              float d = fmaf(dz, dz, fmaf(dy, dy, dx * dx));
              bool hit = alive && (d <= Rsq);
              surv[min(cnt, QCAP) * 256 + tid] = (ushort)(base + t);  // always-store
              bool ovf = hit && (cnt >= QCAP);
              cnt += hit ? 1 : 0;
              // lossless overflow: rare wave-uniform branch, direct ins16
              if (__builtin_expect(__ballot(ovf) != 0, 0)) {
                int m = __builtin_amdgcn_readlane(__float_as_int(vc.w), t);
                ull key = (((ull)__float_as_uint(d)) << 13) | (uint)(m & 8191);
                if (ovf && key < K[15]) ins16(K, key);
              }
            }
            vc = vn;
          }
        }
      }
    } else if (w == 0) {
      // safety full-scan (effectively never taken); wave 0 only -> no dup keys
      if (__ballot(alive)) {
        for (int i = 0; i < N1; ++i) {
          float4 v = arr[i];
          float dx = q.x - v.x, dy = q.y - v.y, dz = q.z - v.z;
          float d = fmaf(dz, dz, fmaf(dy, dy, dx * dx));
          ull key = (((ull)__float_as_uint(d)) << 13) |
                    (uint)(__float_as_int(v.w));
          if (alive && key < K[15]) ins16(K, key);
        }
      }
    }
    cnts[tid] = (uint)cnt;
    __syncthreads();
    int total = (int)(cnts[lane] + cnts[64 + lane] +
                      cnts[128 + lane] + cnts[192 + lane]);
    bool fail = alive && (total < 16) && (attempt < 6);
    if (tid == 0) again = 0;
    __syncthreads();
    if (fail) {
      again = 1;                      // benign LDS race (all write 1)
      R *= 2.f;
      Rsq = R * R;
      cnt = 0;
      #pragma unroll
      for (int s = 0; s < 16; ++s) K[s] = ~0ull;
    }
    alive = (attempt >= 6) ? false : fail;
    attempt++;
    __syncthreads();
    if (!again) break;                // block-uniform
  }

  // ---- resolve: each wave turns its survivor list into a sorted top-16 ----
  int listcnt = min(cnt, QCAP);
  int mx = listcnt;
  #pragma unroll
  for (int o = 32; o; o >>= 1) mx = max(mx, __shfl_xor(mx, o));
  for (int s = 0; s < mx; ++s) {
    bool act = s < listcnt;
    int pos = surv[s * 256 + tid] & 8191;
    float4 v = arr[pos];
    float dx = q.x - v.x, dy = q.y - v.y, dz = q.z - v.z;
    float d = fmaf(dz, dz, fmaf(dy, dy, dx * dx));
    ull key = (((ull)__float_as_uint(d)) << 13) | (uint)(__float_as_int(v.w));
    key = act ? key : ~0ull;
    ins16(K, key);
  }
  #pragma unroll
  for (int s = 0; s < 16; ++s) keysL[s * 256 + tid] = K[s];
  __syncthreads();

  if (w == 0) {
    // merge the 4 sorted 16-lists (exact lowest-16 set; order-free mean)
    #pragma unroll
    for (int ww = 1; ww < 4; ++ww) {
      ull M[16];
      #pragma unroll
      for (int s = 0; s < 16; ++s) {
        ull bk = keysL[(15 - s) * 256 + ww * 64 + lane];   // reversed partner
        M[s] = (K[s] < bk) ? K[s] : bk;                    // bitonic lower half
      }
#define CEK(i, j) { ull a_ = M[i], c_ = M[j]; \
                    M[i] = (a_ < c_) ? a_ : c_; M[j] = (a_ < c_) ? c_ : a_; }
      CEK(0, 8) CEK(1, 9) CEK(2, 10) CEK(3, 11)
      CEK(4, 12) CEK(5, 13) CEK(6, 14) CEK(7, 15)
      CEK(0, 4) CEK(1, 5) CEK(2, 6) CEK(3, 7)
      CEK(8, 12) CEK(9, 13) CEK(10, 14) CEK(11, 15)
      CEK(0, 2) CEK(1, 3) CEK(4, 6) CEK(5, 7)
      CEK(8, 10) CEK(9, 11) CEK(12, 14) CEK(13, 15)
      CEK(0, 1) CEK(2, 3) CEK(4, 5) CEK(6, 7)
      CEK(8, 9) CEK(10, 11) CEK(12, 13) CEK(14, 15)
#undef CEK
      #pragma unroll
      for (int s = 0; s < 16; ++s) K[s] = M[s];
    }
    // gather flows + output
    const float4* __restrict__ fp = f1p + ((size_t)b << 13);
    float fx = 0.f, fy = 0.f, fz = 0.f;
    #pragma unroll
    for (int s = 0; s < 16; ++s) {
      float4 f = fp[(uint)(K[s] & 8191u)];
      fx += f.x; fy += f.y; fz += f.z;
    }
    float* op = out + b * 3 * N2;
    op[n]          = q.x - fx * 0.0625f;
    op[N2 + n]     = q.y - fy * 0.0625f;
    op[2 * N2 + n] = q.z - fz * 0.0625f;
  }
}

extern "C" void kernel_launch(void* const* d_in, const int* in_sizes, int n_in,
                              void* d_out, int out_size, void* d_ws, size_t ws_size,
                              hipStream_t stream) {
  const float* xyz1  = (const float*)d_in[0];
  const float* xyz2  = (const float*)d_in[1];
  const float* flow1 = (const float*)d_in[2];
  float* out = (float*)d_out;

  char* w = (char*)d_ws;
  float4* sp4x = (float4*)w;  w += (size_t)NBATCH * N1 * sizeof(float4);   // 256 KB
  float4* sp4r = (float4*)w;  w += (size_t)NBATCH * N1 * sizeof(float4);   // 256 KB
  float4* f1p  = (float4*)w;  w += (size_t)NBATCH * N1 * sizeof(float4);   // 256 KB
  float4* qs4  = (float4*)w;  w += (size_t)NBATCH * N2 * sizeof(float4);   // 256 KB
  float* qR    = (float*)w;   w += (size_t)NBATCH * N2 * sizeof(float);    // 64 KB
  int* gkey    = (int*)w;     w += (size_t)NBATCH * N2 * sizeof(int);      // 64 KB
  float* gR    = (float*)w;   w += (size_t)NBATCH * N2 * sizeof(float);    // 64 KB
  uint* offsx  = (uint*)w;    w += NBATCH * NBK * sizeof(uint);            // 4 KB
  uint* offsr  = (uint*)w;    w += NBATCH * NBK * sizeof(uint);            // 4 KB

  pw3_build<<<NBATCH, 1024, 0, stream>>>(xyz1, flow1, sp4x, sp4r, f1p, offsx, offsr);
  pw3_qprep<<<(NBATCH * N2) / 256, 256, 0, stream>>>(xyz2, offsx, offsr, gkey, gR);
  pw3_qsort<<<NBATCH, 1024, 0, stream>>>(xyz2, gkey, gR, qs4, qR);
  pw3_sweep<<<NBATCH * 128, 256, 0, stream>>>(sp4x, sp4r, f1p, offsx, offsr,
                                              qs4, qR, out);
}

// Round 11
// 289.668 us; speedup vs baseline: 2.9809x; 1.0339x over previous
//
#include <hip/hip_runtime.h>
#include <math.h>

#define N1 8192
#define N2 8192
#define NBATCH 2
#define NBK 512            // candidate buckets per coordinate
#define QBK 1024           // query sort buckets: (mode<<9) | coordbucket
#define QCAP 40            // per-wave per-lane survivor capacity (+1 scratch row)
#define SWT 512            // sweep block threads (8 waves)

typedef unsigned int uint;
typedef unsigned short ushort;
typedef unsigned long long ull;

__device__ __forceinline__ int bux(float x) {
  int b = (int)floorf((x + 4.0f) * 64.0f);
  return min(max(b, 0), NBK - 1);
}
__device__ __forceinline__ int bur(float r) {
  int b = (int)floorf(r * 64.0f);
  return min(max(b, 0), NBK - 1);
}
// Insert key into ascending sorted 16-array (branchless bubble).
__device__ __forceinline__ void ins16(ull* K, ull key) {
  #pragma unroll
  for (int s = 0; s < 16; ++s) {
    bool lt = key < K[s];
    ull mn = lt ? key : K[s];
    ull mx = lt ? K[s] : key;
    K[s] = mn;
    key = mx;
  }
}
__device__ __forceinline__ float rlf(float v, int l) {
  return __builtin_bit_cast(
      float, __builtin_amdgcn_readlane(__builtin_bit_cast(int, v), l));
}

// Merge my ascending 16-list K with partner ascending 16-list at base
// (read reversed) -> lowest-16, bitonic clean. Exact set semantics.
__device__ __forceinline__ void merge_from(const ull* base, int lane, ull* K) {
  ull M[16];
  #pragma unroll
  for (int s = 0; s < 16; ++s) {
    ull bk = base[(15 - s) * 64 + lane];
    M[s] = (K[s] < bk) ? K[s] : bk;
  }
#define CEK(i, j) { ull a_ = M[i], c_ = M[j]; \
                    M[i] = (a_ < c_) ? a_ : c_; M[j] = (a_ < c_) ? c_ : a_; }
  CEK(0, 8) CEK(1, 9) CEK(2, 10) CEK(3, 11)
  CEK(4, 12) CEK(5, 13) CEK(6, 14) CEK(7, 15)
  CEK(0, 4) CEK(1, 5) CEK(2, 6) CEK(3, 7)
  CEK(8, 12) CEK(9, 13) CEK(10, 14) CEK(11, 15)
  CEK(0, 2) CEK(1, 3) CEK(4, 6) CEK(5, 7)
  CEK(8, 10) CEK(9, 11) CEK(12, 14) CEK(13, 15)
  CEK(0, 1) CEK(2, 3) CEK(4, 5) CEK(6, 7)
  CEK(8, 9) CEK(10, 11) CEK(12, 13) CEK(14, 15)
#undef CEK
  #pragma unroll
  for (int s = 0; s < 16; ++s) K[s] = M[s];
}

// ---------- build: candidates sorted by x-bucket AND |p|-bucket; packed flows ----------
__global__ __launch_bounds__(1024) void pw3_build(
    const float* __restrict__ xyz1, const float* __restrict__ flow1,
    float4* __restrict__ sp4x, float4* __restrict__ sp4r,
    float4* __restrict__ f1p, uint* __restrict__ offsx, uint* __restrict__ offsr) {
  __shared__ uint hx[NBK], hr[NBK], sx[NBK], sr[NBK];
  int b = blockIdx.x, t = threadIdx.x;
  if (t < NBK) { hx[t] = 0; hr[t] = 0; }
  __syncthreads();
  const float* x1 = xyz1 + b * 3 * N1;
  const float* f1 = flow1 + b * 3 * N1;
  float px[8], py[8], pz[8];
  int bkx[8], bkr[8];
  #pragma unroll
  for (int r = 0; r < 8; ++r) {
    int m = r * 1024 + t;
    float fx = f1[m], fy = f1[N1 + m], fz = f1[2 * N1 + m];
    px[r] = x1[m] + fx;
    py[r] = x1[N1 + m] + fy;
    pz[r] = x1[2 * N1 + m] + fz;
    f1p[(b << 13) + m] = make_float4(fx, fy, fz, 0.f);
    bkx[r] = bux(px[r]);
    bkr[r] = bur(sqrtf(px[r] * px[r] + py[r] * py[r] + pz[r] * pz[r]));
    atomicAdd(&hx[bkx[r]], 1u);
    atomicAdd(&hr[bkr[r]], 1u);
  }
  __syncthreads();
  uint vx = 0, vr = 0;
  if (t < NBK) { vx = hx[t]; vr = hr[t]; sx[t] = vx; sr[t] = vr; }
  __syncthreads();
  for (int off = 1; off < NBK; off <<= 1) {
    uint ax = 0, ar = 0;
    if (t < NBK && t >= off) { ax = sx[t - off]; ar = sr[t - off]; }
    __syncthreads();
    if (t < NBK) { sx[t] += ax; sr[t] += ar; }
    __syncthreads();
  }
  if (t < NBK) {
    uint ex = sx[t] - vx, er = sr[t] - vr;
    offsx[(b << 9) + t] = ex;
    offsr[(b << 9) + t] = er;
    hx[t] = ex;   // reuse as cursors
    hr[t] = er;
  }
  __syncthreads();
  #pragma unroll
  for (int r = 0; r < 8; ++r) {
    int m = r * 1024 + t;
    float4 v = make_float4(px[r], py[r], pz[r], __int_as_float(m));
    uint p1 = atomicAdd(&hx[bkx[r]], 1u);
    sp4x[(b << 13) + p1] = v;
    uint p2 = atomicAdd(&hr[bkr[r]], 1u);
    sp4r[(b << 13) + p2] = v;
  }
}

// ---------- qprep (grid-wide): per-query radius R + sort key ----------
__global__ __launch_bounds__(256) void pw3_qprep(
    const float* __restrict__ xyz2, const uint* __restrict__ offsx,
    const uint* __restrict__ offsr, int* __restrict__ gkey,
    float* __restrict__ gR) {
  int i = blockIdx.x * 256 + threadIdx.x;   // 0 .. B*N2-1
  int b = i >> 13, n = i & 8191;
  const float* x2 = xyz2 + b * 3 * N2;
  float X = x2[n], Y = x2[N2 + n], Z = x2[2 * N2 + n];
  float rr = X * X + Y * Y + Z * Z;
  const float T = 70.f;             // box target -> ball count ~ 35 >= 16 w.h.p.
  const float IS2 = 0.70360f;       // 1/(sigma*sqrt(2)), sigma^2 = 1.01
  float R = cbrtf(3.2225e-2f * expf(rr * 0.49505f));
  R = fminf(R, 6.f);
  #pragma unroll
  for (int it = 0; it < 4; ++it) {
    float g = 8192.f
      * (0.5f * (erff((X + R) * IS2) - erff((X - R) * IS2)))
      * (0.5f * (erff((Y + R) * IS2) - erff((Y - R) * IS2)))
      * (0.5f * (erff((Z + R) * IS2) - erff((Z - R) * IS2)));
    R = R * cbrtf(T / fmaxf(g, 1.f));
    R = fminf(R, 8.f);
  }
  R *= 1.05f;
  float rl = sqrtf(rr);
  int bxl = bux(X - R), bxh = bux(X + R);
  int brl = bur(rl - R), brh = bur(rl + R);
  uint jx1 = offsx[(b << 9) + bxl];
  uint jx2 = (bxh >= NBK - 1) ? 8192u : offsx[(b << 9) + bxh + 1];
  uint jr1 = offsr[(b << 9) + brl];
  uint jr2 = (brh >= NBK - 1) ? 8192u : offsr[(b << 9) + brh + 1];
  int mode = ((jr2 - jr1) < (jx2 - jx1)) ? 1 : 0;
  int cb = mode ? bur(rl) : bux(X);
  gkey[i] = (mode << 9) | cb;
  gR[i] = R;
}

// ---------- qsort: counting-sort queries by precomputed key ----------
__global__ __launch_bounds__(1024) void pw3_qsort(
    const float* __restrict__ xyz2, const int* __restrict__ gkey,
    const float* __restrict__ gR, float4* __restrict__ qs4,
    float* __restrict__ qR) {
  __shared__ uint hq[QBK], sq[QBK];
  int b = blockIdx.x, t = threadIdx.x;
  hq[t] = 0;
  __syncthreads();
  int key[8];
  #pragma unroll
  for (int r = 0; r < 8; ++r) {
    key[r] = gkey[(b << 13) + r * 1024 + t];
    atomicAdd(&hq[key[r]], 1u);
  }
  __syncthreads();
  uint v = hq[t];
  sq[t] = v;
  __syncthreads();
  for (int off = 1; off < QBK; off <<= 1) {
    uint a = 0;
    if (t >= off) a = sq[t - off];
    __syncthreads();
    sq[t] += a;
    __syncthreads();
  }
  hq[t] = sq[t] - v;   // cursor
  __syncthreads();
  const float* x2 = xyz2 + b * 3 * N2;
  #pragma unroll
  for (int r = 0; r < 8; ++r) {
    int n = r * 1024 + t;
    uint pos = atomicAdd(&hq[key[r]], 1u);
    int mode = key[r] >> 9;
    qs4[(b << 13) + pos] = make_float4(x2[n], x2[N2 + n], x2[2 * N2 + n],
                                       __int_as_float(n | (mode << 13)));
    qR[(b << 13) + pos] = gR[(b << 13) + n];
  }
}

// ---------- sweep: 8 waves per 64-query group; branchless lane-per-query ----------
__global__ __launch_bounds__(SWT) void pw3_sweep(
    const float4* __restrict__ sp4x, const float4* __restrict__ sp4r,
    const float4* __restrict__ f1p, const uint* __restrict__ offsx,
    const uint* __restrict__ offsr, const float4* __restrict__ qs4,
    const float* __restrict__ qR, float* __restrict__ out) {
  // union: surv (QCAP+1)*SWT ushort = 41984 B  /  merge buf 4*16*64 ull = 32768 B
  __shared__ ull shm[5248];
  __shared__ uint cnts[SWT];
  __shared__ int again;
  ushort* surv = (ushort*)shm;
  ull* buf = shm;

  int tid = threadIdx.x;
  int lane = tid & 63;
  int w = tid >> 6;                  // wave 0..7
  int g = blockIdx.x;
  int b = g >> 7, grp = g & 127;

  float4 q = qs4[(b << 13) + grp * 64 + lane];
  int payload = __float_as_int(q.w);
  int n = payload & 8191;
  int mode = (__builtin_amdgcn_readlane(payload, 0) >> 13) & 1;  // group mode
  const float4* __restrict__ arr = mode ? sp4r + ((size_t)b << 13)
                                        : sp4x + ((size_t)b << 13);
  const uint* __restrict__ offs = mode ? offsr + (b << 9) : offsx + (b << 9);
  float cc = mode ? sqrtf(q.x * q.x + q.y * q.y + q.z * q.z) : q.x;
  float R = qR[(b << 13) + grp * 64 + lane];
  float Rsq = R * R;

  ull K[16];
  #pragma unroll
  for (int s = 0; s < 16; ++s) K[s] = ~0ull;
  int cnt = 0;
  bool alive = true;
  int attempt = 0;

  while (true) {
    if (attempt < 6) {
      int blo_ = mode ? bur(cc - R) : bux(cc - R);
      int bhi_ = mode ? bur(cc + R) : bux(cc + R);
      uint jlo = offs[blo_];
      uint jhi = (bhi_ >= NBK - 1) ? 8192u : offs[bhi_ + 1];
      int cl = alive ? (int)(jlo >> 6) : 0x7FFFFFFF;
      int ch = alive ? (int)((jhi + 63) >> 6) : -1;
      #pragma unroll
      for (int o = 32; o; o >>= 1) {
        cl = min(cl, __shfl_xor(cl, o));
        ch = max(ch, __shfl_xor(ch, o));
      }
      if (cl < ch) {
        int nch = ch - cl;
        int mc0 = cl + (nch * w) / 8;       // this wave's chunk sub-range
        int mc1 = cl + (nch * (w + 1)) / 8;
        if (mc0 < mc1) {
          float4 vc = arr[mc0 * 64 + lane];
          for (int c = mc0; c < mc1; ++c) {
            int cn = (c + 1 < mc1) ? c + 1 : c;
            float4 vn = arr[cn * 64 + lane];     // prefetch next chunk
            int base = c * 64;
            int cntA = cnt;
            // ---- branchless hot loop: 64 candidates, full ILP ----
            #pragma unroll
            for (int t = 0; t < 64; ++t) {
              float sxx = rlf(vc.x, t), syy = rlf(vc.y, t), szz = rlf(vc.z, t);
              float dx = q.x - sxx, dy = q.y - syy, dz = q.z - szz;
              float d = fmaf(dz, dz, fmaf(dy, dy, dx * dx));
              bool hit = alive && (d <= Rsq);
              surv[min(cnt, QCAP) * SWT + tid] = (ushort)(base + t);  // always-store
              cnt += hit ? 1 : 0;
            }
            // ---- rare per-chunk lossless overflow redo ----
            if (__builtin_expect(
                    __ballot((cnt > QCAP) && (cnt > cntA)) != 0ull, 0)) {
              float4 rv = arr[c * 64 + lane];
              int c2 = cntA;
              #pragma unroll 1
              for (int t = 0; t < 64; ++t) {
                float sxx = rlf(rv.x, t), syy = rlf(rv.y, t), szz = rlf(rv.z, t);
                float dx = q.x - sxx, dy = q.y - syy, dz = q.z - szz;
                float d = fmaf(dz, dz, fmaf(dy, dy, dx * dx));
                bool hit2 = alive && (d <= Rsq);
                bool ovf = hit2 && (c2 >= QCAP);
                c2 += hit2 ? 1 : 0;
                if (__ballot(ovf)) {
                  int m = __builtin_amdgcn_readlane(__float_as_int(rv.w), t) & 8191;
                  ull key = (((ull)__float_as_uint(d)) << 13) | (uint)m;
                  if (ovf && key < K[15]) ins16(K, key);
                }
              }
            }
            vc = vn;
          }
        }
      }
    } else if (w == 0) {
      // safety full-scan (effectively never taken); wave 0 only -> no dup keys
      if (__ballot(alive)) {
        for (int i = 0; i < N1; ++i) {
          float4 v = arr[i];
          float dx = q.x - v.x, dy = q.y - v.y, dz = q.z - v.z;
          float d = fmaf(dz, dz, fmaf(dy, dy, dx * dx));
          ull key = (((ull)__float_as_uint(d)) << 13) |
                    (uint)(__float_as_int(v.w) & 8191);
          if (alive && key < K[15]) ins16(K, key);
        }
      }
    }
    cnts[tid] = (uint)cnt;
    __syncthreads();
    int total = 0;
    #pragma unroll
    for (int ww = 0; ww < 8; ++ww) total += (int)cnts[ww * 64 + lane];
    bool fail = alive && (total < 16) && (attempt < 6);
    if (tid == 0) again = 0;
    __syncthreads();
    if (fail) {
      again = 1;                      // benign LDS race (all write 1)
      R *= 2.f;
      Rsq = R * R;
      cnt = 0;
      #pragma unroll
      for (int s = 0; s < 16; ++s) K[s] = ~0ull;
    }
    alive = (attempt >= 6) ? false : fail;
    attempt++;
    __syncthreads();
    if (!again) break;                // block-uniform
  }

  // ---- resolve: each wave turns its survivor list into a sorted top-16 ----
  int listcnt = min(cnt, QCAP);
  int mx = listcnt;
  #pragma unroll
  for (int o = 32; o; o >>= 1) mx = max(mx, __shfl_xor(mx, o));
  for (int s = 0; s < mx; ++s) {
    bool act = s < listcnt;
    int pos = surv[s * SWT + tid] & 8191;
    float4 v = arr[pos];
    float dx = q.x - v.x, dy = q.y - v.y, dz = q.z - v.z;
    float d = fmaf(dz, dz, fmaf(dy, dy, dx * dx));
    ull key = (((ull)__float_as_uint(d)) << 13) |
              (uint)(__float_as_int(v.w) & 8191);
    key = act ? key : ~0ull;
    ins16(K, key);
  }
  __syncthreads();   // all surv reads done before buf (aliased) writes

  // ---- tree merge of 8 sorted 16-lists: 8 -> 4 -> 2 -> 1 ----
  if (w >= 4) {
    #pragma unroll
    for (int s = 0; s < 16; ++s) buf[((w - 4) * 16 + s) * 64 + lane] = K[s];
  }
  __syncthreads();
  if (w < 4) merge_from(buf + (w * 16) * 64, lane, K);
  __syncthreads();
  if (w == 2 || w == 3) {
    #pragma unroll
    for (int s = 0; s < 16; ++s) buf[((w - 2) * 16 + s) * 64 + lane] = K[s];
  }
  __syncthreads();
  if (w < 2) merge_from(buf + (w * 16) * 64, lane, K);
  __syncthreads();
  if (w == 1) {
    #pragma unroll
    for (int s = 0; s < 16; ++s) buf[s * 64 + lane] = K[s];
  }
  __syncthreads();

  if (w == 0) {
    merge_from(buf, lane, K);
    // gather flows in ascending (d, idx) order == top_k order
    const float4* __restrict__ fp = f1p + ((size_t)b << 13);
    float fx = 0.f, fy = 0.f, fz = 0.f;
    #pragma unroll
    for (int s = 0; s < 16; ++s) {
      float4 f = fp[(uint)(K[s] & 8191u)];
      fx += f.x; fy += f.y; fz += f.z;
    }
    float* op = out + b * 3 * N2;
    op[n]          = q.x - fx * 0.0625f;
    op[N2 + n]     = q.y - fy * 0.0625f;
    op[2 * N2 + n] = q.z - fz * 0.0625f;
  }
}

extern "C" void kernel_launch(void* const* d_in, const int* in_sizes, int n_in,
                              void* d_out, int out_size, void* d_ws, size_t ws_size,
                              hipStream_t stream) {
  const float* xyz1  = (const float*)d_in[0];
  const float* xyz2  = (const float*)d_in[1];
  const float* flow1 = (const float*)d_in[2];
  float* out = (float*)d_out;

  char* w = (char*)d_ws;
  float4* sp4x = (float4*)w;  w += (size_t)NBATCH * N1 * sizeof(float4);   // 256 KB
  float4* sp4r = (float4*)w;  w += (size_t)NBATCH * N1 * sizeof(float4);   // 256 KB
  float4* f1p  = (float4*)w;  w += (size_t)NBATCH * N1 * sizeof(float4);   // 256 KB
  float4* qs4  = (float4*)w;  w += (size_t)NBATCH * N2 * sizeof(float4);   // 256 KB
  float* qR    = (float*)w;   w += (size_t)NBATCH * N2 * sizeof(float);    // 64 KB
  int* gkey    = (int*)w;     w += (size_t)NBATCH * N2 * sizeof(int);      // 64 KB
  float* gR    = (float*)w;   w += (size_t)NBATCH * N2 * sizeof(float);    // 64 KB
  uint* offsx  = (uint*)w;    w += NBATCH * NBK * sizeof(uint);            // 4 KB
  uint* offsr  = (uint*)w;    w += NBATCH * NBK * sizeof(uint);            // 4 KB

  pw3_build<<<NBATCH, 1024, 0, stream>>>(xyz1, flow1, sp4x, sp4r, f1p, offsx, offsr);
  pw3_qprep<<<(NBATCH * N2) / 256, 256, 0, stream>>>(xyz2, offsx, offsr, gkey, gR);
  pw3_qsort<<<NBATCH, 1024, 0, stream>>>(xyz2, gkey, gR, qs4, qR);
  pw3_sweep<<<NBATCH * 128, SWT, 0, stream>>>(sp4x, sp4r, f1p, offsx, offsr,
                                              qs4, qR, out);
}